// Round 1
// baseline (389.518 us; speedup 1.0000x reference)
//
#include <hip/hip_runtime.h>

// LongTermMemoryMLP: 3 batched NT-GEMMs with per-batch weights.
//   h0 = relu(q  @ W0^T + b0)   [8,4096,512]x[8,1024,512]^T
//   h1 = relu(h0 @ W1^T + b1)   [8,4096,1024]x[8,1024,1024]^T
//   out =      h1 @ W2^T + b2   [8,4096,1024]x[8,512,1024]^T  (fp32 out)
// Compute in f16 MFMA (no fp32 MFMA on CDNA4), fp32 accumulate.
// Round 0: m93-class structure (128x128 tile, BK=32, 4 waves x 4x4 mfma_16x16x32).

typedef _Float16 f16x8 __attribute__((ext_vector_type(8)));
typedef _Float16 f16x4 __attribute__((ext_vector_type(4)));
typedef float    f32x4 __attribute__((ext_vector_type(4)));

// ---- fp32 -> f16 cast (grid-stride, float4 in / f16x4 out) ----
__global__ __launch_bounds__(256) void cast_f32_f16(const float* __restrict__ src,
                                                    _Float16* __restrict__ dst,
                                                    int n4) {
    int i = blockIdx.x * 256 + threadIdx.x;
    const int stride = gridDim.x * 256;
    for (; i < n4; i += stride) {
        float4 f = reinterpret_cast<const float4*>(src)[i];
        f16x4 o;
        o[0] = (_Float16)f.x; o[1] = (_Float16)f.y;
        o[2] = (_Float16)f.z; o[3] = (_Float16)f.w;
        reinterpret_cast<f16x4*>(dst)[i] = o;
    }
}

// load 8 source elements (contiguous k) as f16x8 bit-packed in a uint4
template <bool SRC_F16>
__device__ __forceinline__ uint4 load8(const char* p) {
    if constexpr (SRC_F16) {
        return *reinterpret_cast<const uint4*>(p);
    } else {
        const float4* fp = reinterpret_cast<const float4*>(p);
        float4 f0 = fp[0], f1 = fp[1];
        f16x8 o;
        o[0] = (_Float16)f0.x; o[1] = (_Float16)f0.y;
        o[2] = (_Float16)f0.z; o[3] = (_Float16)f0.w;
        o[4] = (_Float16)f1.x; o[5] = (_Float16)f1.y;
        o[6] = (_Float16)f1.z; o[7] = (_Float16)f1.w;
        return __builtin_bit_cast(uint4, o);
    }
}

// C[b,m,n] = sum_k A[b,m,k] * W[b,n,k] + bias[b,n]  (both operands K-contiguous)
// Tile: 128x128, BK=32. 256 threads = 4 waves in 2x2; each wave 64x64 via
// 4x4 x mfma_f32_16x16x32_f16.
// A-frag layout: A[m=lane&15][k=(lane>>4)*8+j]; B-frag mirrors with n=lane&15.
// C/D: col=lane&15, row=(lane>>4)*4+reg   [measured m89/m91].
template <bool A_F16, bool W_F16, bool RELU, bool OUT_F16>
__global__ __launch_bounds__(256) void gemm_bias_act(
    const void* __restrict__ Av, const void* __restrict__ Wv,
    const float* __restrict__ bias, void* __restrict__ Outv,
    int M, int N, int K) {
    constexpr int BM = 128, BN = 128, BK = 32;
    __shared__ __align__(16) _Float16 As[BM * BK];
    __shared__ __align__(16) _Float16 Bs[BN * BK];

    const int tid  = threadIdx.x;
    const int lane = tid & 63;
    const int wave = tid >> 6;
    const int rowl = lane & 15;
    const int q    = lane >> 4;
    const int q8   = q * 8;
    const int wm   = (wave >> 1) * 64;
    const int wn   = (wave & 1) * 64;

    const int bm = blockIdx.x, bn = blockIdx.y, b = blockIdx.z;

    // staging geometry: 512 chunks of 8 f16; chunk c -> row c>>2, k (c&3)*8
    const int c0 = tid, c1 = tid + 256;
    const int ar0 = c0 >> 2, ak0 = (c0 & 3) * 8;
    const int ar1 = c1 >> 2, ak1 = (c1 & 3) * 8;

    constexpr size_t esA = A_F16 ? 2 : 4;
    constexpr size_t esW = W_F16 ? 2 : 4;
    const char* Abase = (const char*)Av;
    const char* Wbase = (const char*)Wv;

    size_t aoff0 = ((size_t)b * M * K + (size_t)(bm * BM + ar0) * K + ak0) * esA;
    size_t aoff1 = ((size_t)b * M * K + (size_t)(bm * BM + ar1) * K + ak1) * esA;
    size_t woff0 = ((size_t)b * N * K + (size_t)(bn * BN + ar0) * K + ak0) * esW;
    size_t woff1 = ((size_t)b * N * K + (size_t)(bn * BN + ar1) * K + ak1) * esW;

    f32x4 acc[4][4];
#pragma unroll
    for (int mi = 0; mi < 4; ++mi)
#pragma unroll
        for (int ni = 0; ni < 4; ++ni)
            acc[mi][ni] = (f32x4){0.f, 0.f, 0.f, 0.f};

    const int nk = K / BK;
    for (int kk = 0; kk < nk; ++kk) {
        uint4 va0 = load8<A_F16>(Abase + aoff0);
        uint4 va1 = load8<A_F16>(Abase + aoff1);
        uint4 vw0 = load8<W_F16>(Wbase + woff0);
        uint4 vw1 = load8<W_F16>(Wbase + woff1);
        aoff0 += BK * esA; aoff1 += BK * esA;
        woff0 += BK * esW; woff1 += BK * esW;

        __syncthreads();  // previous iteration's frag reads done
        *(uint4*)(As + ar0 * BK + ak0) = va0;
        *(uint4*)(As + ar1 * BK + ak1) = va1;
        *(uint4*)(Bs + ar0 * BK + ak0) = vw0;
        *(uint4*)(Bs + ar1 * BK + ak1) = vw1;
        __syncthreads();

        f16x8 af[4], bf[4];
#pragma unroll
        for (int i = 0; i < 4; ++i)
            af[i] = *(const f16x8*)(As + (wm + i * 16 + rowl) * BK + q8);
#pragma unroll
        for (int i = 0; i < 4; ++i)
            bf[i] = *(const f16x8*)(Bs + (wn + i * 16 + rowl) * BK + q8);
#pragma unroll
        for (int mi = 0; mi < 4; ++mi)
#pragma unroll
            for (int ni = 0; ni < 4; ++ni)
                acc[mi][ni] = __builtin_amdgcn_mfma_f32_16x16x32_f16(
                    af[mi], bf[ni], acc[mi][ni], 0, 0, 0);
    }

    // epilogue: bias (+relu) and store
    float bcol[4];
    {
        const float* bp = bias + (size_t)b * N + bn * BN + wn;
#pragma unroll
        for (int ni = 0; ni < 4; ++ni) bcol[ni] = bp[ni * 16 + rowl];
    }
#pragma unroll
    for (int mi = 0; mi < 4; ++mi) {
        const int row0 = bm * BM + wm + mi * 16 + q * 4;
#pragma unroll
        for (int r = 0; r < 4; ++r) {
            const size_t ro = (size_t)b * M * N + (size_t)(row0 + r) * N + bn * BN + wn;
#pragma unroll
            for (int ni = 0; ni < 4; ++ni) {
                float v = acc[mi][ni][r] + bcol[ni];
                if (RELU) v = fmaxf(v, 0.f);
                if (OUT_F16)
                    ((_Float16*)Outv)[ro + ni * 16 + rowl] = (_Float16)v;
                else
                    ((float*)Outv)[ro + ni * 16 + rowl] = v;
            }
        }
    }
}

extern "C" void kernel_launch(void* const* d_in, const int* in_sizes, int n_in,
                              void* d_out, int out_size, void* d_ws, size_t ws_size,
                              hipStream_t stream) {
    const int B = 8, S = 4096, DI = 512, DH = 1024, DO = 512;
    const float* query = (const float*)d_in[0];
    const float* W0    = (const float*)d_in[1];
    const float* b0    = (const float*)d_in[2];
    const float* W1    = (const float*)d_in[3];
    const float* b1    = (const float*)d_in[4];
    const float* W2    = (const float*)d_in[5];
    const float* b2    = (const float*)d_in[6];

    char* ws = (char*)d_ws;
    const size_t nH  = (size_t)B * S * DH;   // 33.5M
    const size_t nQ  = (size_t)B * S * DI;   // 16.8M
    const size_t nW0 = (size_t)B * DH * DI;  // 4.2M
    const size_t nW1 = (size_t)B * DH * DH;  // 8.4M
    const size_t nW2 = (size_t)B * DO * DH;  // 4.2M

    _Float16* h0 = (_Float16*)ws;             // 64 MiB
    _Float16* h1 = (_Float16*)(ws + nH * 2);  // 64 MiB
    const size_t off_casts = nH * 4;
    const size_t full_need = off_casts + (nQ + nW0 + nW1 + nW2) * 2;  // 192 MiB

    const dim3 blk(256);
    const dim3 g0(S / 128, DH / 128, B);
    const dim3 g2(S / 128, DO / 128, B);

    if (ws_size >= full_need) {
        // fast path: pre-cast everything to f16 (pure-BW, ~30us), f16 staging in GEMMs
        _Float16* qf  = (_Float16*)(ws + off_casts);
        _Float16* w0f = qf + nQ;
        _Float16* w1f = w0f + nW0;
        _Float16* w2f = w1f + nW1;
        cast_f32_f16<<<dim3(1024), blk, 0, stream>>>(query, qf,  (int)(nQ / 4));
        cast_f32_f16<<<dim3(1024), blk, 0, stream>>>(W0,    w0f, (int)(nW0 / 4));
        cast_f32_f16<<<dim3(1024), blk, 0, stream>>>(W1,    w1f, (int)(nW1 / 4));
        cast_f32_f16<<<dim3(1024), blk, 0, stream>>>(W2,    w2f, (int)(nW2 / 4));
        gemm_bias_act<true, true, true,  true ><<<g0, blk, 0, stream>>>(qf, w0f, b0, h0, S, DH, DI);
        gemm_bias_act<true, true, true,  true ><<<g0, blk, 0, stream>>>(h0, w1f, b1, h1, S, DH, DH);
        gemm_bias_act<true, true, false, false><<<g2, blk, 0, stream>>>(h1, w2f, b2, d_out, S, DO, DH);
    } else {
        // fallback: convert fp32 -> f16 during LDS staging (needs only 128 MiB ws)
        gemm_bias_act<false, false, true,  true ><<<g0, blk, 0, stream>>>(query, W0, b0, h0, S, DH, DI);
        gemm_bias_act<true,  false, true,  true ><<<g0, blk, 0, stream>>>(h0, W1, b1, h1, S, DH, DH);
        gemm_bias_act<true,  false, false, false><<<g2, blk, 0, stream>>>(h1, W2, b2, d_out, S, DO, DH);
    }
}

// Round 2
// 382.132 us; speedup vs baseline: 1.0193x; 1.0193x over previous
//
#include <hip/hip_runtime.h>

// LongTermMemoryMLP: 3 batched NT-GEMMs with per-batch weights.
//   h0 = relu(q  @ W0^T + b0)   [8,4096,512]x[8,1024,512]^T
//   h1 = relu(h0 @ W1^T + b1)   [8,4096,1024]x[8,1024,1024]^T
//   out =      h1 @ W2^T + b2   [8,4096,1024]x[8,512,1024]^T  (fp32 out)
// f16 MFMA, fp32 accumulate. Round 2: global_load_lds width=16 staging
// (m93->m97 ladder step), merged cast kernel.

typedef _Float16 f16x8 __attribute__((ext_vector_type(8)));
typedef _Float16 f16x4 __attribute__((ext_vector_type(4)));
typedef float    f32x4 __attribute__((ext_vector_type(4)));

// async global->LDS DMA, 16B per lane. LDS dest must be wave-uniform base
// + lane*16 (m104/m108) — our chunk layout guarantees this.
__device__ __forceinline__ void stage16(const void* g, void* l) {
    __builtin_amdgcn_global_load_lds(
        (const __attribute__((address_space(1))) unsigned int*)g,
        (__attribute__((address_space(3))) unsigned int*)l,
        16, 0, 0);
}

// ---- fp32 -> f16 casts, all four arrays in one launch ----
__device__ __forceinline__ void cast_seg(const float* __restrict__ s,
                                         _Float16* __restrict__ d, int n4) {
    const int stride = gridDim.x * 256;
    for (int i = blockIdx.x * 256 + threadIdx.x; i < n4; i += stride) {
        float4 f = reinterpret_cast<const float4*>(s)[i];
        f16x4 o;
        o[0] = (_Float16)f.x; o[1] = (_Float16)f.y;
        o[2] = (_Float16)f.z; o[3] = (_Float16)f.w;
        reinterpret_cast<f16x4*>(d)[i] = o;
    }
}

__global__ __launch_bounds__(256) void cast_all(
    const float* s0, _Float16* d0, int n0,
    const float* s1, _Float16* d1, int n1,
    const float* s2, _Float16* d2, int n2,
    const float* s3, _Float16* d3, int n3) {
    cast_seg(s0, d0, n0);
    cast_seg(s1, d1, n1);
    cast_seg(s2, d2, n2);
    cast_seg(s3, d3, n3);
}

// load 8 f32 elements, convert to f16x8 packed in uint4 (fallback staging)
__device__ __forceinline__ uint4 load8f32(const char* p) {
    const float4* fp = reinterpret_cast<const float4*>(p);
    float4 f0 = fp[0], f1 = fp[1];
    f16x8 o;
    o[0] = (_Float16)f0.x; o[1] = (_Float16)f0.y;
    o[2] = (_Float16)f0.z; o[3] = (_Float16)f0.w;
    o[4] = (_Float16)f1.x; o[5] = (_Float16)f1.y;
    o[6] = (_Float16)f1.z; o[7] = (_Float16)f1.w;
    return __builtin_bit_cast(uint4, o);
}

// C[b,m,n] = sum_k A[b,m,k] * W[b,n,k] + bias[b,n]
// 128x128 tile, BK=32, 4 waves (2x2), each wave 4x4 x mfma_f32_16x16x32_f16.
// f16 operands staged via global_load_lds dwordx4; f32 operands via VGPR+cvt.
template <bool A_F16, bool W_F16, bool RELU, bool OUT_F16>
__global__ __launch_bounds__(256) void gemm_bias_act(
    const void* __restrict__ Av, const void* __restrict__ Wv,
    const float* __restrict__ bias, void* __restrict__ Outv,
    int M, int N, int K) {
    constexpr int BM = 128, BN = 128, BK = 32;
    __shared__ __align__(16) _Float16 As[BM * BK];
    __shared__ __align__(16) _Float16 Bs[BN * BK];

    const int tid  = threadIdx.x;
    const int lane = tid & 63;
    const int rowl = lane & 15;
    const int q8   = (lane >> 4) * 8;
    const int wm   = ((tid >> 6) >> 1) * 64;
    const int wn   = ((tid >> 6) & 1) * 64;

    const int bm = blockIdx.x, bn = blockIdx.y, b = blockIdx.z;

    // chunk c (0..511, 8 f16 each): row c>>2, k (c&3)*8; LDS half-offset 8c.
    const int c0 = tid, c1 = tid + 256;
    const int ar0 = c0 >> 2, ak0 = (c0 & 3) * 8;
    const int ar1 = c1 >> 2, ak1 = (c1 & 3) * 8;

    constexpr size_t esA = A_F16 ? 2 : 4;
    constexpr size_t esW = W_F16 ? 2 : 4;
    const char* Abase = (const char*)Av;
    const char* Wbase = (const char*)Wv;

    size_t aoff0 = ((size_t)b * M * K + (size_t)(bm * BM + ar0) * K + ak0) * esA;
    size_t aoff1 = ((size_t)b * M * K + (size_t)(bm * BM + ar1) * K + ak1) * esA;
    size_t woff0 = ((size_t)b * N * K + (size_t)(bn * BN + ar0) * K + ak0) * esW;
    size_t woff1 = ((size_t)b * N * K + (size_t)(bn * BN + ar1) * K + ak1) * esW;

    f32x4 acc[4][4];
#pragma unroll
    for (int mi = 0; mi < 4; ++mi)
#pragma unroll
        for (int ni = 0; ni < 4; ++ni)
            acc[mi][ni] = (f32x4){0.f, 0.f, 0.f, 0.f};

    const int nk = K / BK;
    for (int kk = 0; kk < nk; ++kk) {
        uint4 va0, va1, vw0, vw1;
        if (!A_F16) { va0 = load8f32(Abase + aoff0); va1 = load8f32(Abase + aoff1); }
        if (!W_F16) { vw0 = load8f32(Wbase + woff0); vw1 = load8f32(Wbase + woff1); }

        __syncthreads();  // prev iteration's frag reads complete
        if (A_F16) {
            stage16(Abase + aoff0, As + 8 * (size_t)c0);
            stage16(Abase + aoff1, As + 8 * (size_t)c1);
        } else {
            *(uint4*)(As + ar0 * BK + ak0) = va0;
            *(uint4*)(As + ar1 * BK + ak1) = va1;
        }
        if (W_F16) {
            stage16(Wbase + woff0, Bs + 8 * (size_t)c0);
            stage16(Wbase + woff1, Bs + 8 * (size_t)c1);
        } else {
            *(uint4*)(Bs + ar0 * BK + ak0) = vw0;
            *(uint4*)(Bs + ar1 * BK + ak1) = vw1;
        }
        aoff0 += BK * esA; aoff1 += BK * esA;
        woff0 += BK * esW; woff1 += BK * esW;
        __syncthreads();  // vmcnt(0) drain: DMA + ds_write visible

        f16x8 af[4], bf[4];
#pragma unroll
        for (int i = 0; i < 4; ++i)
            af[i] = *(const f16x8*)(As + (wm + i * 16 + rowl) * BK + q8);
#pragma unroll
        for (int i = 0; i < 4; ++i)
            bf[i] = *(const f16x8*)(Bs + (wn + i * 16 + rowl) * BK + q8);
#pragma unroll
        for (int mi = 0; mi < 4; ++mi)
#pragma unroll
            for (int ni = 0; ni < 4; ++ni)
                acc[mi][ni] = __builtin_amdgcn_mfma_f32_16x16x32_f16(
                    af[mi], bf[ni], acc[mi][ni], 0, 0, 0);
    }

    // epilogue: bias (+relu), store
    const int q = lane >> 4;
    float bcol[4];
    {
        const float* bp = bias + (size_t)b * N + bn * BN + wn;
#pragma unroll
        for (int ni = 0; ni < 4; ++ni) bcol[ni] = bp[ni * 16 + rowl];
    }
#pragma unroll
    for (int mi = 0; mi < 4; ++mi) {
        const int row0 = bm * BM + wm + mi * 16 + q * 4;
#pragma unroll
        for (int r = 0; r < 4; ++r) {
            const size_t ro = (size_t)b * M * N + (size_t)(row0 + r) * N + bn * BN + wn;
#pragma unroll
            for (int ni = 0; ni < 4; ++ni) {
                float v = acc[mi][ni][r] + bcol[ni];
                if (RELU) v = fmaxf(v, 0.f);
                if (OUT_F16)
                    ((_Float16*)Outv)[ro + ni * 16 + rowl] = (_Float16)v;
                else
                    ((float*)Outv)[ro + ni * 16 + rowl] = v;
            }
        }
    }
}

extern "C" void kernel_launch(void* const* d_in, const int* in_sizes, int n_in,
                              void* d_out, int out_size, void* d_ws, size_t ws_size,
                              hipStream_t stream) {
    const int B = 8, S = 4096, DI = 512, DH = 1024, DO = 512;
    const float* query = (const float*)d_in[0];
    const float* W0    = (const float*)d_in[1];
    const float* b0    = (const float*)d_in[2];
    const float* W1    = (const float*)d_in[3];
    const float* b1    = (const float*)d_in[4];
    const float* W2    = (const float*)d_in[5];
    const float* b2    = (const float*)d_in[6];

    char* ws = (char*)d_ws;
    const size_t nH  = (size_t)B * S * DH;   // 33.5M
    const size_t nQ  = (size_t)B * S * DI;   // 16.8M
    const size_t nW0 = (size_t)B * DH * DI;  // 4.2M
    const size_t nW1 = (size_t)B * DH * DH;  // 8.4M
    const size_t nW2 = (size_t)B * DO * DH;  // 4.2M

    _Float16* h0 = (_Float16*)ws;             // 64 MiB
    _Float16* h1 = (_Float16*)(ws + nH * 2);  // 64 MiB
    const size_t off_casts = nH * 4;
    const size_t full_need = off_casts + (nQ + nW0 + nW1 + nW2) * 2;  // 192 MiB

    const dim3 blk(256);
    const dim3 g0(S / 128, DH / 128, B);
    const dim3 g2(S / 128, DO / 128, B);

    if (ws_size >= full_need) {
        // fast path: pre-cast inputs to f16, all-DMA staging in GEMMs
        _Float16* qf  = (_Float16*)(ws + off_casts);
        _Float16* w0f = qf + nQ;
        _Float16* w1f = w0f + nW0;
        _Float16* w2f = w1f + nW1;
        cast_all<<<dim3(2048), blk, 0, stream>>>(
            query, qf, (int)(nQ / 4), W0, w0f, (int)(nW0 / 4),
            W1, w1f, (int)(nW1 / 4), W2, w2f, (int)(nW2 / 4));
        gemm_bias_act<true, true, true,  true ><<<g0, blk, 0, stream>>>(qf, w0f, b0, h0, S, DH, DI);
        gemm_bias_act<true, true, true,  true ><<<g0, blk, 0, stream>>>(h0, w1f, b1, h1, S, DH, DH);
        gemm_bias_act<true, true, false, false><<<g2, blk, 0, stream>>>(h1, w2f, b2, d_out, S, DO, DH);
    } else {
        // fallback (needs 128 MiB): f32 weights converted during staging;
        // f16 A operand still uses DMA staging for GEMM1/2
        gemm_bias_act<false, false, true,  true ><<<g0, blk, 0, stream>>>(query, W0, b0, h0, S, DH, DI);
        gemm_bias_act<true,  false, true,  true ><<<g0, blk, 0, stream>>>(h0, W1, b1, h1, S, DH, DH);
        gemm_bias_act<true,  false, false, false><<<g2, blk, 0, stream>>>(h1, W2, b2, d_out, S, DO, DH);
    }
}

// Round 3
// 358.771 us; speedup vs baseline: 1.0857x; 1.0651x over previous
//
#include <hip/hip_runtime.h>

// LongTermMemoryMLP: 3 batched NT-GEMMs with per-batch weights.
//   h0 = relu(q  @ W0^T + b0)   [8,4096,512]x[8,1024,512]^T
//   h1 = relu(h0 @ W1^T + b1)   [8,4096,1024]x[8,1024,1024]^T
//   out =      h1 @ W2^T + b2   [8,4096,1024]x[8,512,1024]^T  (fp32 out)
// f16 MFMA, fp32 accumulate.
// Round 3: single-barrier double-buffered global_load_lds pipeline —
// prefetch tile k+1 issued right after the barrier, so the vmcnt(0) drain
// at the next barrier waits on a DMA that had the whole compute phase to land.

typedef _Float16 f16x8 __attribute__((ext_vector_type(8)));
typedef _Float16 f16x4 __attribute__((ext_vector_type(4)));
typedef float    f32x4 __attribute__((ext_vector_type(4)));

// async global->LDS DMA, 16B per lane; LDS dest = wave-uniform base + lane*16.
__device__ __forceinline__ void stage16(const void* g, void* l) {
    __builtin_amdgcn_global_load_lds(
        (const __attribute__((address_space(1))) unsigned int*)g,
        (__attribute__((address_space(3))) unsigned int*)l,
        16, 0, 0);
}

// ---- fp32 -> f16 casts, all four arrays in one launch ----
__device__ __forceinline__ void cast_seg(const float* __restrict__ s,
                                         _Float16* __restrict__ d, int n4) {
    const int stride = gridDim.x * 256;
    for (int i = blockIdx.x * 256 + threadIdx.x; i < n4; i += stride) {
        float4 f = reinterpret_cast<const float4*>(s)[i];
        f16x4 o;
        o[0] = (_Float16)f.x; o[1] = (_Float16)f.y;
        o[2] = (_Float16)f.z; o[3] = (_Float16)f.w;
        reinterpret_cast<f16x4*>(d)[i] = o;
    }
}

__global__ __launch_bounds__(256) void cast_all(
    const float* s0, _Float16* d0, int n0,
    const float* s1, _Float16* d1, int n1,
    const float* s2, _Float16* d2, int n2,
    const float* s3, _Float16* d3, int n3) {
    cast_seg(s0, d0, n0);
    cast_seg(s1, d1, n1);
    cast_seg(s2, d2, n2);
    cast_seg(s3, d3, n3);
}

// ---- pipelined all-f16 GEMM: C[b,m,n] = sum_k A[b,m,k]*W[b,n,k] + bias[b,n]
// 128x128 tile, BK=32, 4 waves (2x2), each wave 4x4 x mfma_f32_16x16x32_f16.
// LDS double-buffered (2 x 16 KB); ONE barrier per K-iteration.
template <bool RELU, bool OUT_F16>
__global__ __launch_bounds__(256) void gemm_dbuf(
    const _Float16* __restrict__ A, const _Float16* __restrict__ W,
    const float* __restrict__ bias, void* __restrict__ Outv,
    int M, int N, int K) {
    constexpr int BM = 128, BN = 128, BK = 32;
    __shared__ __align__(16) _Float16 As[2][BM * BK];
    __shared__ __align__(16) _Float16 Bs[2][BN * BK];

    const int tid  = threadIdx.x;
    const int lane = tid & 63;
    const int rowl = lane & 15;
    const int q8   = (lane >> 4) * 8;
    const int wm   = ((tid >> 6) >> 1) * 64;
    const int wn   = ((tid >> 6) & 1) * 64;

    const int bm = blockIdx.x, bn = blockIdx.y, b = blockIdx.z;

    // chunk c (0..511, 8 f16 = 16 B each): source row c>>2, k (c&3)*8;
    // LDS dest f16-offset 8*c  (contiguous lane*16B — DMA constraint).
    const int c0 = tid, c1 = tid + 256;
    const int ar0 = c0 >> 2, ak0 = (c0 & 3) * 8;
    const int ar1 = c1 >> 2, ak1 = (c1 & 3) * 8;

    const char* Ab = (const char*)(A + (size_t)b * M * K + (size_t)(bm * BM) * K);
    const char* Wb = (const char*)(W + (size_t)b * N * K + (size_t)(bn * BN) * K);
    size_t aoff0 = ((size_t)ar0 * K + ak0) * 2;
    size_t aoff1 = ((size_t)ar1 * K + ak1) * 2;
    size_t woff0 = ((size_t)ar0 * K + ak0) * 2;
    size_t woff1 = ((size_t)ar1 * K + ak1) * 2;

    f32x4 acc[4][4];
#pragma unroll
    for (int mi = 0; mi < 4; ++mi)
#pragma unroll
        for (int ni = 0; ni < 4; ++ni)
            acc[mi][ni] = (f32x4){0.f, 0.f, 0.f, 0.f};

    // prologue: stage tile 0 into buffer 0
    stage16(Ab + aoff0, &As[0][8 * (size_t)c0]);
    stage16(Ab + aoff1, &As[0][8 * (size_t)c1]);
    stage16(Wb + woff0, &Bs[0][8 * (size_t)c0]);
    stage16(Wb + woff1, &Bs[0][8 * (size_t)c1]);
    aoff0 += BK * 2; aoff1 += BK * 2; woff0 += BK * 2; woff1 += BK * 2;

    const int nk = K / BK;
    for (int kk = 0; kk < nk; ++kk) {
        const int cur = kk & 1;
        // barrier: drains vmcnt(0) -> tile kk DMA landed; also guarantees all
        // waves finished reading the buffer we are about to prefetch into.
        __syncthreads();
        if (kk + 1 < nk) {
            const int nxt = cur ^ 1;
            stage16(Ab + aoff0, &As[nxt][8 * (size_t)c0]);
            stage16(Ab + aoff1, &As[nxt][8 * (size_t)c1]);
            stage16(Wb + woff0, &Bs[nxt][8 * (size_t)c0]);
            stage16(Wb + woff1, &Bs[nxt][8 * (size_t)c1]);
            aoff0 += BK * 2; aoff1 += BK * 2; woff0 += BK * 2; woff1 += BK * 2;
        }

        f16x8 af[4], bf[4];
#pragma unroll
        for (int i = 0; i < 4; ++i)
            af[i] = *(const f16x8*)(&As[cur][(wm + i * 16 + rowl) * BK + q8]);
#pragma unroll
        for (int i = 0; i < 4; ++i)
            bf[i] = *(const f16x8*)(&Bs[cur][(wn + i * 16 + rowl) * BK + q8]);
#pragma unroll
        for (int mi = 0; mi < 4; ++mi)
#pragma unroll
            for (int ni = 0; ni < 4; ++ni)
                acc[mi][ni] = __builtin_amdgcn_mfma_f32_16x16x32_f16(
                    af[mi], bf[ni], acc[mi][ni], 0, 0, 0);
    }

    // epilogue: bias (+relu), store. C/D: col=lane&15, row=(lane>>4)*4+reg.
    const int q = lane >> 4;
    float bcol[4];
    {
        const float* bp = bias + (size_t)b * N + bn * BN + wn;
#pragma unroll
        for (int ni = 0; ni < 4; ++ni) bcol[ni] = bp[ni * 16 + rowl];
    }
#pragma unroll
    for (int mi = 0; mi < 4; ++mi) {
        const int row0 = bm * BM + wm + mi * 16 + q * 4;
#pragma unroll
        for (int r = 0; r < 4; ++r) {
            const size_t ro = (size_t)b * M * N + (size_t)(row0 + r) * N + bn * BN + wn;
#pragma unroll
            for (int ni = 0; ni < 4; ++ni) {
                float v = acc[mi][ni][r] + bcol[ni];
                if (RELU) v = fmaxf(v, 0.f);
                if (OUT_F16)
                    ((_Float16*)Outv)[ro + ni * 16 + rowl] = (_Float16)v;
                else
                    ((float*)Outv)[ro + ni * 16 + rowl] = v;
            }
        }
    }
}

// ---- legacy 2-barrier kernel, mixed f32/f16 operands (fallback path only) ----
__device__ __forceinline__ uint4 load8f32(const char* p) {
    const float4* fp = reinterpret_cast<const float4*>(p);
    float4 f0 = fp[0], f1 = fp[1];
    f16x8 o;
    o[0] = (_Float16)f0.x; o[1] = (_Float16)f0.y;
    o[2] = (_Float16)f0.z; o[3] = (_Float16)f0.w;
    o[4] = (_Float16)f1.x; o[5] = (_Float16)f1.y;
    o[6] = (_Float16)f1.z; o[7] = (_Float16)f1.w;
    return __builtin_bit_cast(uint4, o);
}

template <bool A_F16, bool W_F16, bool RELU, bool OUT_F16>
__global__ __launch_bounds__(256) void gemm_bias_act(
    const void* __restrict__ Av, const void* __restrict__ Wv,
    const float* __restrict__ bias, void* __restrict__ Outv,
    int M, int N, int K) {
    constexpr int BM = 128, BN = 128, BK = 32;
    __shared__ __align__(16) _Float16 As[BM * BK];
    __shared__ __align__(16) _Float16 Bs[BN * BK];

    const int tid  = threadIdx.x;
    const int lane = tid & 63;
    const int rowl = lane & 15;
    const int q8   = (lane >> 4) * 8;
    const int wm   = ((tid >> 6) >> 1) * 64;
    const int wn   = ((tid >> 6) & 1) * 64;
    const int bm = blockIdx.x, bn = blockIdx.y, b = blockIdx.z;

    const int c0 = tid, c1 = tid + 256;
    const int ar0 = c0 >> 2, ak0 = (c0 & 3) * 8;
    const int ar1 = c1 >> 2, ak1 = (c1 & 3) * 8;

    constexpr size_t esA = A_F16 ? 2 : 4;
    constexpr size_t esW = W_F16 ? 2 : 4;
    const char* Abase = (const char*)Av;
    const char* Wbase = (const char*)Wv;

    size_t aoff0 = ((size_t)b * M * K + (size_t)(bm * BM + ar0) * K + ak0) * esA;
    size_t aoff1 = ((size_t)b * M * K + (size_t)(bm * BM + ar1) * K + ak1) * esA;
    size_t woff0 = ((size_t)b * N * K + (size_t)(bn * BN + ar0) * K + ak0) * esW;
    size_t woff1 = ((size_t)b * N * K + (size_t)(bn * BN + ar1) * K + ak1) * esW;

    f32x4 acc[4][4];
#pragma unroll
    for (int mi = 0; mi < 4; ++mi)
#pragma unroll
        for (int ni = 0; ni < 4; ++ni)
            acc[mi][ni] = (f32x4){0.f, 0.f, 0.f, 0.f};

    const int nk = K / BK;
    for (int kk = 0; kk < nk; ++kk) {
        uint4 va0, va1, vw0, vw1;
        if (!A_F16) { va0 = load8f32(Abase + aoff0); va1 = load8f32(Abase + aoff1); }
        if (!W_F16) { vw0 = load8f32(Wbase + woff0); vw1 = load8f32(Wbase + woff1); }
        __syncthreads();
        if (A_F16) {
            stage16(Abase + aoff0, As + 8 * (size_t)c0);
            stage16(Abase + aoff1, As + 8 * (size_t)c1);
        } else {
            *(uint4*)(As + ar0 * BK + ak0) = va0;
            *(uint4*)(As + ar1 * BK + ak1) = va1;
        }
        if (W_F16) {
            stage16(Wbase + woff0, Bs + 8 * (size_t)c0);
            stage16(Wbase + woff1, Bs + 8 * (size_t)c1);
        } else {
            *(uint4*)(Bs + ar0 * BK + ak0) = vw0;
            *(uint4*)(Bs + ar1 * BK + ak1) = vw1;
        }
        aoff0 += BK * esA; aoff1 += BK * esA;
        woff0 += BK * esW; woff1 += BK * esW;
        __syncthreads();

        f16x8 af[4], bf[4];
#pragma unroll
        for (int i = 0; i < 4; ++i)
            af[i] = *(const f16x8*)(As + (wm + i * 16 + rowl) * BK + q8);
#pragma unroll
        for (int i = 0; i < 4; ++i)
            bf[i] = *(const f16x8*)(Bs + (wn + i * 16 + rowl) * BK + q8);
#pragma unroll
        for (int mi = 0; mi < 4; ++mi)
#pragma unroll
            for (int ni = 0; ni < 4; ++ni)
                acc[mi][ni] = __builtin_amdgcn_mfma_f32_16x16x32_f16(
                    af[mi], bf[ni], acc[mi][ni], 0, 0, 0);
    }

    const int q = lane >> 4;
    float bcol[4];
    {
        const float* bp = bias + (size_t)b * N + bn * BN + wn;
#pragma unroll
        for (int ni = 0; ni < 4; ++ni) bcol[ni] = bp[ni * 16 + rowl];
    }
#pragma unroll
    for (int mi = 0; mi < 4; ++mi) {
        const int row0 = bm * BM + wm + mi * 16 + q * 4;
#pragma unroll
        for (int r = 0; r < 4; ++r) {
            const size_t ro = (size_t)b * M * N + (size_t)(row0 + r) * N + bn * BN + wn;
#pragma unroll
            for (int ni = 0; ni < 4; ++ni) {
                float v = acc[mi][ni][r] + bcol[ni];
                if (RELU) v = fmaxf(v, 0.f);
                if (OUT_F16)
                    ((_Float16*)Outv)[ro + ni * 16 + rowl] = (_Float16)v;
                else
                    ((float*)Outv)[ro + ni * 16 + rowl] = v;
            }
        }
    }
}

extern "C" void kernel_launch(void* const* d_in, const int* in_sizes, int n_in,
                              void* d_out, int out_size, void* d_ws, size_t ws_size,
                              hipStream_t stream) {
    const int B = 8, S = 4096, DI = 512, DH = 1024, DO = 512;
    const float* query = (const float*)d_in[0];
    const float* W0    = (const float*)d_in[1];
    const float* b0    = (const float*)d_in[2];
    const float* W1    = (const float*)d_in[3];
    const float* b1    = (const float*)d_in[4];
    const float* W2    = (const float*)d_in[5];
    const float* b2    = (const float*)d_in[6];

    char* ws = (char*)d_ws;
    const size_t nH  = (size_t)B * S * DH;   // 33.5M
    const size_t nQ  = (size_t)B * S * DI;   // 16.8M
    const size_t nW0 = (size_t)B * DH * DI;  // 4.2M
    const size_t nW1 = (size_t)B * DH * DH;  // 8.4M
    const size_t nW2 = (size_t)B * DO * DH;  // 4.2M

    _Float16* h0 = (_Float16*)ws;             // 64 MiB
    _Float16* h1 = (_Float16*)(ws + nH * 2);  // 64 MiB
    const size_t off_casts = nH * 4;
    const size_t full_need = off_casts + (nQ + nW0 + nW1 + nW2) * 2;  // 192 MiB

    const dim3 blk(256);
    const dim3 g0(S / 128, DH / 128, B);
    const dim3 g2(S / 128, DO / 128, B);

    if (ws_size >= full_need) {
        _Float16* qf  = (_Float16*)(ws + off_casts);
        _Float16* w0f = qf + nQ;
        _Float16* w1f = w0f + nW0;
        _Float16* w2f = w1f + nW1;
        cast_all<<<dim3(2048), blk, 0, stream>>>(
            query, qf, (int)(nQ / 4), W0, w0f, (int)(nW0 / 4),
            W1, w1f, (int)(nW1 / 4), W2, w2f, (int)(nW2 / 4));
        gemm_dbuf<true,  true ><<<g0, blk, 0, stream>>>(qf, w0f, b0, h0, S, DH, DI);
        gemm_dbuf<true,  true ><<<g0, blk, 0, stream>>>(h0, w1f, b1, h1, S, DH, DH);
        gemm_dbuf<false, false><<<g2, blk, 0, stream>>>(h1, w2f, b2, d_out, S, DO, DH);
    } else {
        gemm_bias_act<false, false, true,  true ><<<g0, blk, 0, stream>>>(query, W0, b0, h0, S, DH, DI);
        gemm_bias_act<true,  false, true,  true ><<<g0, blk, 0, stream>>>(h0, W1, b1, h1, S, DH, DH);
        gemm_bias_act<true,  false, false, false><<<g2, blk, 0, stream>>>(h1, W2, b2, d_out, S, DO, DH);
    }
}